// Round 9
// baseline (29.656 us; speedup 1.0000x reference)
//
#include <hip/hip_runtime.h>
#include <math.h>

// B=1, N=4096 queries, F=4096 faces (fixed by reference setup_inputs).
#define N_Q 4096
#define N_F 4096
#define QPT 2                  // queries per thread, packed as f32x2 lanes
#define QBLK (256 * QPT)       // 512 queries per block
#define FSPLIT 128             // 8 q-blocks x 128 f-splits = 1024 blocks (4/CU)
#define FT (N_F / FSPLIT)      // 32 faces per block
#define INV_2PI 0.15915494309189535f

typedef __attribute__((ext_vector_type(2))) float f32x2;
typedef __attribute__((ext_vector_type(4))) float f32x4;

static __device__ __forceinline__ f32x2 fma2(f32x2 a, f32x2 b, f32x2 c) {
    return __builtin_elementwise_fma(a, b, c);   // -> v_pk_fma_f32
}
static __device__ __forceinline__ f32x2 splat(float x) { return (f32x2){x, x}; }
static __device__ __forceinline__ f32x2 lo2(f32x4 v) { return __builtin_shufflevector(v, v, 0, 1); }
static __device__ __forceinline__ f32x2 hi2(f32x4 v) { return __builtin_shufflevector(v, v, 2, 3); }

// Packed fast atan2 for two (y,x) pairs. Poly + range reduction packed,
// rcp/quadrant fixups scalar per element. Max err ~1e-5 rad.
static __device__ __forceinline__ f32x2 fast_atan2_2(f32x2 y, f32x2 x) {
    const float pi   = 3.14159265358979f;
    const float pi_2 = 1.57079632679490f;
    f32x2 ax = __builtin_elementwise_abs(x);
    f32x2 ay = __builtin_elementwise_abs(y);
    f32x2 mx = __builtin_elementwise_max(ax, ay);
    f32x2 mn = __builtin_elementwise_min(ax, ay);
    mx = __builtin_elementwise_max(mx, splat(1e-30f));   // 0/0 -> 0, no NaN
    f32x2 rc = { __builtin_amdgcn_rcpf(mx.x), __builtin_amdgcn_rcpf(mx.y) };
    f32x2 t = mn * rc;                                   // in [0,1]
    f32x2 s = t * t;
    f32x2 p = splat(-0.0117212f);
    p = fma2(p, s, splat( 0.05265332f));
    p = fma2(p, s, splat(-0.11643287f));
    p = fma2(p, s, splat( 0.19354346f));
    p = fma2(p, s, splat(-0.33262347f));
    p = fma2(p, s, splat( 0.99997726f));
    f32x2 r = p * t;                                     // atan(t) on [0, pi/4]
    float r0 = (ay.x > ax.x) ? (pi_2 - r.x) : r.x;
    float r1 = (ay.y > ax.y) ? (pi_2 - r.y) : r.y;
    r0 = (x.x < 0.0f) ? (pi - r0) : r0;
    r1 = (x.y < 0.0f) ? (pi - r1) : r1;
    return (f32x2){ copysignf(r0, y.x), copysignf(r1, y.y) };
}

// Single dispatch. Face constants live in LDS PRE-DUPLICATED ({s,s,t,t} per
// float4) so each broadcast ds_read_b128 yields two ready f32x2 splat
// operands (adjacent VGPR pairs) -> v_pk_fma_f32 with zero splat-movs.
// Layout per face (10 float4 slots):
//  0:{Ax,Ax,Ay,Ay} 1:{Az,Az,|a|2,|a|2} 2:{Bx..By} 3:{Bz..|b|2} 4:{Cx..Cy}
//  5:{Cz..|c|2}    6:{Nx,Nx,Ny,Ny}     7:{Nz,Nz,D,D}
//  8:{ab,ab,bc,bc} 9:{ac,ac,0,0}
__global__ __launch_bounds__(256) void winding_kernel(
    const float* __restrict__ qp,   // [N_Q][3]
    const float* __restrict__ fc,   // [N_F][9]
    float* __restrict__ out)        // [N_Q]
{
    __shared__ float raw[FT * 9];
    __shared__ f32x4 cst[FT][10];

    const int tid = threadIdx.x;

    // Stage this block's face slice: FT*9 = 288 dwords = 72 float4s.
    {
        const f32x4* src = (const f32x4*)(fc + (size_t)blockIdx.y * FT * 9);
        f32x4* dst = (f32x4*)raw;
        if (tid < FT * 9 / 4) dst[tid] = src[tid];
    }
    __syncthreads();

    // Threads 0..FT-1: one face's constants each.
    // n = bxc + cxa + axb ; D = a.(bxc)
    if (tid < FT) {
        const float* v = &raw[tid * 9];
        const float ax = v[0], ay = v[1], az = v[2];
        const float bx = v[3], by = v[4], bz = v[5];
        const float cx = v[6], cy = v[7], cz = v[8];
        const float ux = by*cz - bz*cy, uy = bz*cx - bx*cz, uz = bx*cy - by*cx; // bxc
        const float vx = cy*az - cz*ay, vy = cz*ax - cx*az, vz = cx*ay - cy*ax; // cxa
        const float wx = ay*bz - az*by, wy = az*bx - ax*bz, wz = ax*by - ay*bx; // axb
        const float D  = ax*ux + ay*uy + az*uz;
        const float Pa = ax*ax + ay*ay + az*az;
        const float Pb = bx*bx + by*by + bz*bz;
        const float Pc = cx*cx + cy*cy + cz*cz;
        cst[tid][0] = (f32x4){ax, ax, ay, ay};
        cst[tid][1] = (f32x4){az, az, Pa, Pa};
        cst[tid][2] = (f32x4){bx, bx, by, by};
        cst[tid][3] = (f32x4){bz, bz, Pb, Pb};
        cst[tid][4] = (f32x4){cx, cx, cy, cy};
        cst[tid][5] = (f32x4){cz, cz, Pc, Pc};
        cst[tid][6] = (f32x4){ux + vx + wx, ux + vx + wx, uy + vy + wy, uy + vy + wy};
        cst[tid][7] = (f32x4){uz + vz + wz, uz + vz + wz, D, D};
        const float kab = ax*bx + ay*by + az*bz;
        const float kbc = bx*cx + by*cy + bz*cz;
        const float kac = ax*cx + ay*cy + az*cz;
        cst[tid][8] = (f32x4){kab, kab, kbc, kbc};
        cst[tid][9] = (f32x4){kac, kac, 0.0f, 0.0f};
    }
    __syncthreads();

    const int q0 = blockIdx.x * QBLK + tid;
    const int q1 = q0 + 256;
    // Hoisted NEGATED query (pk ops take these directly, no per-iter neg).
    const f32x2 mqx = {-qp[q0*3+0], -qp[q1*3+0]};
    const f32x2 mqy = {-qp[q0*3+1], -qp[q1*3+1]};
    const f32x2 mqz = {-qp[q0*3+2], -qp[q1*3+2]};
    const f32x2 th  = 0.5f * fma2(mqx, mqx, fma2(mqy, mqy, mqz * mqz));

    f32x2 s = {0.0f, 0.0f};
    #pragma unroll 4
    for (int f = 0; f < FT; ++f) {
        const f32x4 t0 = cst[f][0], t1 = cst[f][1], t2 = cst[f][2];
        const f32x4 t3 = cst[f][3], t4 = cst[f][4], t5 = cst[f][5];
        const f32x4 t6 = cst[f][6], t7 = cst[f][7], t8 = cst[f][8];
        const f32x4 t9 = cst[f][9];

        // d'_x = th - q.x ; |x-q|^2 = |x|^2 + 2 d'_x ;
        // (x-q).(y-q) = x.y + d'_x + d'_y ; det = D - q.n
        const f32x2 da  = fma2(mqx, lo2(t0), fma2(mqy, hi2(t0), fma2(mqz, lo2(t1), th)));
        const f32x2 db  = fma2(mqx, lo2(t2), fma2(mqy, hi2(t2), fma2(mqz, lo2(t3), th)));
        const f32x2 dc  = fma2(mqx, lo2(t4), fma2(mqy, hi2(t4), fma2(mqz, lo2(t5), th)));
        const f32x2 det = fma2(mqx, lo2(t6), fma2(mqy, hi2(t6), fma2(mqz, lo2(t7), hi2(t7))));

        const f32x2 ra = fma2(splat(2.0f), da, hi2(t1));
        const f32x2 rb = fma2(splat(2.0f), db, hi2(t3));
        const f32x2 rc = fma2(splat(2.0f), dc, hi2(t5));
        const f32x2 na = { __builtin_amdgcn_sqrtf(ra.x), __builtin_amdgcn_sqrtf(ra.y) };
        const f32x2 nb = { __builtin_amdgcn_sqrtf(rb.x), __builtin_amdgcn_sqrtf(rb.y) };
        const f32x2 nc = { __builtin_amdgcn_sqrtf(rc.x), __builtin_amdgcn_sqrtf(rc.y) };

        const f32x2 ab = lo2(t8) + (da + db);
        const f32x2 bc = hi2(t8) + (db + dc);
        const f32x2 ac = lo2(t9) + (da + dc);

        const f32x2 den = fma2(na * nb, nc, fma2(bc, na, fma2(ac, nb, ab * nc)));
        s += fast_atan2_2(det, den);
    }

    atomicAdd(&out[q0], s.x * INV_2PI);
    atomicAdd(&out[q1], s.y * INV_2PI);
}

extern "C" void kernel_launch(void* const* d_in, const int* in_sizes, int n_in,
                              void* d_out, int out_size, void* d_ws, size_t ws_size,
                              hipStream_t stream) {
    const float* qp = (const float*)d_in[0];   // query_points (1,4096,3) f32
    const float* fc = (const float*)d_in[1];   // face_coord   (1,4096,3,3) f32
    float* out = (float*)d_out;                // (1,4096) f32

    // Harness poisons d_out once and never re-poisons between replays:
    // we accumulate with atomics, so zero it ourselves every call.
    hipMemsetAsync(out, 0, (size_t)out_size * sizeof(float), stream);

    dim3 grid(N_Q / QBLK, FSPLIT);
    dim3 block(256);
    winding_kernel<<<grid, block, 0, stream>>>(qp, fc, out);
}

// Round 10
// 28.893 us; speedup vs baseline: 1.0264x; 1.0264x over previous
//
#include <hip/hip_runtime.h>
#include <math.h>

// B=1, N=4096 queries, F=4096 faces (fixed by reference setup_inputs).
#define N_Q 4096
#define N_F 4096
#define QPT 4                  // queries per thread: 2 packed f32x2 groups
#define QBLK (256 * QPT)       // 1024 queries per block
#define FSPLIT 256             // 4 q-blocks x 256 f-splits = 1024 blocks (16 waves/CU)
#define FT (N_F / FSPLIT)      // 16 faces per block
#define INV_2PI 0.15915494309189535f

typedef __attribute__((ext_vector_type(2))) float f32x2;
typedef __attribute__((ext_vector_type(4))) float f32x4;

static __device__ __forceinline__ f32x2 fma2(f32x2 a, f32x2 b, f32x2 c) {
    return __builtin_elementwise_fma(a, b, c);   // -> v_pk_fma_f32
}
static __device__ __forceinline__ f32x2 splat(float x) { return (f32x2){x, x}; }
static __device__ __forceinline__ f32x2 lo2(f32x4 v) { return __builtin_shufflevector(v, v, 0, 1); }
static __device__ __forceinline__ f32x2 hi2(f32x4 v) { return __builtin_shufflevector(v, v, 2, 3); }

// Packed fast atan2 for two (y,x) pairs. Max err ~1e-5 rad.
static __device__ __forceinline__ f32x2 fast_atan2_2(f32x2 y, f32x2 x) {
    const float pi   = 3.14159265358979f;
    const float pi_2 = 1.57079632679490f;
    f32x2 ax = __builtin_elementwise_abs(x);
    f32x2 ay = __builtin_elementwise_abs(y);
    f32x2 mx = __builtin_elementwise_max(ax, ay);
    f32x2 mn = __builtin_elementwise_min(ax, ay);
    mx = __builtin_elementwise_max(mx, splat(1e-30f));   // 0/0 -> 0, no NaN
    f32x2 rc = { __builtin_amdgcn_rcpf(mx.x), __builtin_amdgcn_rcpf(mx.y) };
    f32x2 t = mn * rc;                                   // in [0,1]
    f32x2 s = t * t;
    f32x2 p = splat(-0.0117212f);
    p = fma2(p, s, splat( 0.05265332f));
    p = fma2(p, s, splat(-0.11643287f));
    p = fma2(p, s, splat( 0.19354346f));
    p = fma2(p, s, splat(-0.33262347f));
    p = fma2(p, s, splat( 0.99997726f));
    f32x2 r = p * t;                                     // atan(t) on [0, pi/4]
    float r0 = (ay.x > ax.x) ? (pi_2 - r.x) : r.x;
    float r1 = (ay.y > ax.y) ? (pi_2 - r.y) : r.y;
    r0 = (x.x < 0.0f) ? (pi - r0) : r0;
    r1 = (x.y < 0.0f) ? (pi - r1) : r1;
    return (f32x2){ copysignf(r0, y.x), copysignf(r1, y.y) };
}

// Solid-angle terms for two packed (query,face) pairs from dup'd constants.
static __device__ __forceinline__ f32x2 pair2_term(
    f32x2 mqx, f32x2 mqy, f32x2 mqz, f32x2 th,
    f32x4 t0, f32x4 t1, f32x4 t2, f32x4 t3, f32x4 t4,
    f32x4 t5, f32x4 t6, f32x4 t7, f32x4 t8, f32x4 t9)
{
    // d'_x = th - q.x ; |x-q|^2 = |x|^2 + 2 d'_x ;
    // (x-q).(y-q) = x.y + d'_x + d'_y ; det = D - q.n
    const f32x2 da  = fma2(mqx, lo2(t0), fma2(mqy, hi2(t0), fma2(mqz, lo2(t1), th)));
    const f32x2 db  = fma2(mqx, lo2(t2), fma2(mqy, hi2(t2), fma2(mqz, lo2(t3), th)));
    const f32x2 dc  = fma2(mqx, lo2(t4), fma2(mqy, hi2(t4), fma2(mqz, lo2(t5), th)));
    const f32x2 det = fma2(mqx, lo2(t6), fma2(mqy, hi2(t6), fma2(mqz, lo2(t7), hi2(t7))));

    const f32x2 ra = fma2(splat(2.0f), da, hi2(t1));
    const f32x2 rb = fma2(splat(2.0f), db, hi2(t3));
    const f32x2 rc = fma2(splat(2.0f), dc, hi2(t5));
    const f32x2 na = { __builtin_amdgcn_sqrtf(ra.x), __builtin_amdgcn_sqrtf(ra.y) };
    const f32x2 nb = { __builtin_amdgcn_sqrtf(rb.x), __builtin_amdgcn_sqrtf(rb.y) };
    const f32x2 nc = { __builtin_amdgcn_sqrtf(rc.x), __builtin_amdgcn_sqrtf(rc.y) };

    const f32x2 ab = lo2(t8) + (da + db);
    const f32x2 bc = hi2(t8) + (db + dc);
    const f32x2 ac = lo2(t9) + (da + dc);

    const f32x2 den = fma2(na * nb, nc, fma2(bc, na, fma2(ac, nb, ab * nc)));
    return fast_atan2_2(det, den);
}

// Single dispatch. Face constants in LDS pre-duplicated ({s,s,t,t} per
// float4): one broadcast ds_read_b128 -> two ready f32x2 pk operands.
// 10 reads/f-iter now serve FOUR pairs (2 pk groups share the t-regs).
__global__ __launch_bounds__(256) void winding_kernel(
    const float* __restrict__ qp,   // [N_Q][3]
    const float* __restrict__ fc,   // [N_F][9]
    float* __restrict__ out)        // [N_Q]
{
    __shared__ float raw[FT * 9];
    __shared__ f32x4 cst[FT][10];

    const int tid = threadIdx.x;

    // Stage this block's face slice: FT*9 = 144 dwords = 36 float4s.
    {
        const f32x4* src = (const f32x4*)(fc + (size_t)blockIdx.y * FT * 9);
        f32x4* dst = (f32x4*)raw;
        if (tid < FT * 9 / 4) dst[tid] = src[tid];
    }
    __syncthreads();

    // Threads 0..FT-1: one face's constants each.
    // n = bxc + cxa + axb ; D = a.(bxc)
    if (tid < FT) {
        const float* v = &raw[tid * 9];
        const float ax = v[0], ay = v[1], az = v[2];
        const float bx = v[3], by = v[4], bz = v[5];
        const float cx = v[6], cy = v[7], cz = v[8];
        const float ux = by*cz - bz*cy, uy = bz*cx - bx*cz, uz = bx*cy - by*cx; // bxc
        const float vx = cy*az - cz*ay, vy = cz*ax - cx*az, vz = cx*ay - cy*ax; // cxa
        const float wx = ay*bz - az*by, wy = az*bx - ax*bz, wz = ax*by - ay*bx; // axb
        const float D  = ax*ux + ay*uy + az*uz;
        const float Pa = ax*ax + ay*ay + az*az;
        const float Pb = bx*bx + by*by + bz*bz;
        const float Pc = cx*cx + cy*cy + cz*cz;
        cst[tid][0] = (f32x4){ax, ax, ay, ay};
        cst[tid][1] = (f32x4){az, az, Pa, Pa};
        cst[tid][2] = (f32x4){bx, bx, by, by};
        cst[tid][3] = (f32x4){bz, bz, Pb, Pb};
        cst[tid][4] = (f32x4){cx, cx, cy, cy};
        cst[tid][5] = (f32x4){cz, cz, Pc, Pc};
        cst[tid][6] = (f32x4){ux + vx + wx, ux + vx + wx, uy + vy + wy, uy + vy + wy};
        cst[tid][7] = (f32x4){uz + vz + wz, uz + vz + wz, D, D};
        const float kab = ax*bx + ay*by + az*bz;
        const float kbc = bx*cx + by*cy + bz*cz;
        const float kac = ax*cx + ay*cy + az*cz;
        cst[tid][8] = (f32x4){kab, kab, kbc, kbc};
        cst[tid][9] = (f32x4){kac, kac, 0.0f, 0.0f};
    }
    __syncthreads();

    const int q0 = blockIdx.x * QBLK + tid;
    const int q1 = q0 + 256, q2 = q0 + 512, q3 = q0 + 768;
    // Hoisted NEGATED queries, two packed groups A=(q0,q1), B=(q2,q3).
    const f32x2 mqxA = {-qp[q0*3+0], -qp[q1*3+0]};
    const f32x2 mqyA = {-qp[q0*3+1], -qp[q1*3+1]};
    const f32x2 mqzA = {-qp[q0*3+2], -qp[q1*3+2]};
    const f32x2 mqxB = {-qp[q2*3+0], -qp[q3*3+0]};
    const f32x2 mqyB = {-qp[q2*3+1], -qp[q3*3+1]};
    const f32x2 mqzB = {-qp[q2*3+2], -qp[q3*3+2]};
    const f32x2 thA  = 0.5f * fma2(mqxA, mqxA, fma2(mqyA, mqyA, mqzA * mqzA));
    const f32x2 thB  = 0.5f * fma2(mqxB, mqxB, fma2(mqyB, mqyB, mqzB * mqzB));

    f32x2 sA = {0.0f, 0.0f}, sB = {0.0f, 0.0f};
    #pragma unroll 2
    for (int f = 0; f < FT; ++f) {
        const f32x4 t0 = cst[f][0], t1 = cst[f][1], t2 = cst[f][2];
        const f32x4 t3 = cst[f][3], t4 = cst[f][4], t5 = cst[f][5];
        const f32x4 t6 = cst[f][6], t7 = cst[f][7], t8 = cst[f][8];
        const f32x4 t9 = cst[f][9];
        sA += pair2_term(mqxA, mqyA, mqzA, thA, t0,t1,t2,t3,t4,t5,t6,t7,t8,t9);
        sB += pair2_term(mqxB, mqyB, mqzB, thB, t0,t1,t2,t3,t4,t5,t6,t7,t8,t9);
    }

    atomicAdd(&out[q0], sA.x * INV_2PI);
    atomicAdd(&out[q1], sA.y * INV_2PI);
    atomicAdd(&out[q2], sB.x * INV_2PI);
    atomicAdd(&out[q3], sB.y * INV_2PI);
}

extern "C" void kernel_launch(void* const* d_in, const int* in_sizes, int n_in,
                              void* d_out, int out_size, void* d_ws, size_t ws_size,
                              hipStream_t stream) {
    const float* qp = (const float*)d_in[0];   // query_points (1,4096,3) f32
    const float* fc = (const float*)d_in[1];   // face_coord   (1,4096,3,3) f32
    float* out = (float*)d_out;                // (1,4096) f32

    // Harness poisons d_out once and never re-poisons between replays:
    // we accumulate with atomics, so zero it ourselves every call.
    hipMemsetAsync(out, 0, (size_t)out_size * sizeof(float), stream);

    dim3 grid(N_Q / QBLK, FSPLIT);
    dim3 block(256);
    winding_kernel<<<grid, block, 0, stream>>>(qp, fc, out);
}